// Round 5
// baseline (1689.777 us; speedup 1.0000x reference)
//
#include <hip/hip_runtime.h>
#include <hip/hip_bf16.h>
#include <hip/hip_fp16.h>

// ---------------- problem constants (from reference) ----------------
// N = 100000 nodes, E = 1600000 edges, F_IN = 512, H1*C1 = 64, NUM_CLASSES = 40
#define F_IN 512
#define HC1 64          // 8 heads * 8 ch
#define NH1 8
#define NC 40
#define NEG_SLOPE 0.2f
#define RADIX_EPB 4096  // edges per block in scatter1
#define MAXNB2 2048     // max 64-node buckets (N/64 = 1563)
#define BCAP2 2048      // bucket capacity (mean 1024, +32 sigma)

typedef short bf16x8 __attribute__((ext_vector_type(8)));
typedef float f32x4 __attribute__((ext_vector_type(4)));

static __device__ __forceinline__ unsigned short f2b(float f) {
    __hip_bfloat16 h = __float2bfloat16(f);      // RNE
    return *(unsigned short*)&h;
}
static __device__ __forceinline__ float b2f(unsigned short u) {
    union { unsigned int i; float f; } v;
    v.i = ((unsigned int)u) << 16;               // bf16 -> fp32 exact
    return v.f;
}
static __device__ __forceinline__ unsigned short f2h(float f) {
    __half h = __float2half(f);
    return *(unsigned short*)&h;
}

__device__ __forceinline__ float lrelu(float e) { return e > 0.f ? e : NEG_SLOPE * e; }

// ---------------- one-shot param prep + edge dtype detect (fused) ----------------
// blocks 0..15: wst (W1 bf16, k-major, XOR-swizzled LDS image); block 0 also ws2/wd2.
// block 16: int64 detection flag.
__global__ void prep(const float* __restrict__ W1, const float* __restrict__ W2,
                     const float* __restrict__ a_s2, const float* __restrict__ a_d2,
                     const int* __restrict__ ei,
                     unsigned short* __restrict__ wst, float* __restrict__ ws2,
                     float* __restrict__ wd2, int* __restrict__ flag) {
    if (blockIdx.x == 16) {
        __shared__ int found;
        if (threadIdx.x == 0) found = 0;
        __syncthreads();
        for (int i = threadIdx.x; i < 4096; i += 256) {
            if (ei[2 * i + 1] != 0) atomicOr(&found, 1);
        }
        __syncthreads();
        if (threadIdx.x == 0) *flag = (found == 0) ? 1 : 0;   // 1 => int64
        return;
    }
    int t = blockIdx.x * 256 + threadIdx.x;   // 16 x 256 = 4096 slots
    {
        int p  = t & 7;          // physical 16B slot
        int n  = (t >> 3) & 63;  // output column
        int kb = t >> 9;         // 64-wide k block, 0..7
        int l  = p ^ (n & 7);    // logical slot
        int k0 = kb * 64 + l * 8;
        unsigned short v[8];
#pragma unroll
        for (int j = 0; j < 8; j++) v[j] = f2b(W1[(size_t)(k0 + j) * HC1 + n]);
        *(uint4*)(wst + ((size_t)(kb * 64 + n) * 64 + p * 8)) = *(uint4*)v;
    }
    if (blockIdx.x == 0 && threadIdx.x < HC1) {
        int c = threadIdx.x;
        float s = 0.f, d = 0.f;
#pragma unroll
        for (int j = 0; j < NC; j++) {
            float w = W2[c * NC + j];
            s += w * a_s2[j];
            d += w * a_d2[j];
        }
        ws2[c] = s;
        wd2[c] = d;
    }
}

// ---------------- scatter: bin edges into 64-node dst buckets, packed records ------
// record = (src << 6) | (dst & 63); bucket = dst >> 6.
__global__ __launch_bounds__(256) void scatter1(const int* __restrict__ ei, const int* __restrict__ flag,
                                                int* __restrict__ bcnt, int* __restrict__ bpk,
                                                int E, int NB2) {
    __shared__ int cnt[MAXNB2];
    __shared__ int gb[MAXNB2];
    int tid = threadIdx.x;
    for (int i = tid; i < NB2; i += 256) cnt[i] = 0;
    __syncthreads();
    int f = *flag;
    int base = blockIdx.x * RADIX_EPB;
    int pk[16], bk[16], rv[16];
#pragma unroll
    for (int i = 0; i < 16; i++) {
        int e = base + i * 256 + tid;
        if (e < E) {
            int s, d;
            if (f) { s = ei[2 * e]; d = ei[2 * (E + e)]; }
            else   { s = ei[e];     d = ei[E + e]; }
            pk[i] = (s << 6) | (d & 63);
            bk[i] = d >> 6;
            rv[i] = atomicAdd(&cnt[bk[i]], 1);
        }
    }
    __syncthreads();
    for (int i = tid; i < NB2; i += 256) {
        int c = cnt[i];
        gb[i] = c ? atomicAdd(&bcnt[i], c) : 0;
    }
    __syncthreads();
#pragma unroll
    for (int i = 0; i < 16; i++) {
        int e = base + i * 256 + tid;
        if (e < E) {
            int pos = gb[bk[i]] + rv[i];
            if (pos < BCAP2)
                bpk[(size_t)bk[i] * BCAP2 + pos] = pk[i];
        }
    }
}

// ---------------- GEMM1 (bf16 MFMA) + fused alpha1 ----------------
__global__ __launch_bounds__(256) void gemm1(const float* __restrict__ x,
                                             const unsigned short* __restrict__ wst,
                                             const float* __restrict__ a_s, const float* __restrict__ a_d,
                                             unsigned short* __restrict__ h1, float* __restrict__ as1,
                                             float* __restrict__ ad1, int Nn) {
    __shared__ __align__(16) unsigned short smem[8192];   // xs[64][64] | ws[64][64]
    unsigned short* xs = smem;          // swizzled A tile
    unsigned short* ws = smem + 4096;   // swizzled B tile (image == wst tile)
    int tid = threadIdx.x;
    int m0 = blockIdx.x * 64;
    int w = tid >> 6, lane = tid & 63;
    int quad = lane >> 4, mr = lane & 15;
    f32x4 acc[4];
#pragma unroll
    for (int i = 0; i < 4; i++) acc[i] = (f32x4){0.f, 0.f, 0.f, 0.f};

    int srow = tid >> 2;        // 0..63 staged row
    int sseg = tid & 3;         // 16-float segment within 64-wide k chunk
    bool rok = (m0 + srow) < Nn;
    const float* xrow = x + (size_t)(m0 + srow) * F_IN + sseg * 16;
    int swzw = (srow & 7) << 4;             // write-side XOR (bytes)
    int swzr = (mr & 7) << 4;               // read-side XOR (bytes)

    for (int kb = 0; kb < 8; kb++) {
        float4 xv0, xv1, xv2, xv3;
        if (rok) {
            const float4* xp = (const float4*)(xrow + kb * 64);
            xv0 = xp[0]; xv1 = xp[1]; xv2 = xp[2]; xv3 = xp[3];
        } else {
            xv0 = xv1 = xv2 = xv3 = make_float4(0.f, 0.f, 0.f, 0.f);
        }
        const uint4* wp = (const uint4*)(wst + (size_t)kb * 4096);
        uint4 wv0 = wp[tid];
        uint4 wv1 = wp[tid + 256];
        __syncthreads();   // previous iteration's MFMA reads complete
        {
            unsigned short bx[16];
            bx[0]  = f2b(xv0.x); bx[1]  = f2b(xv0.y); bx[2]  = f2b(xv0.z); bx[3]  = f2b(xv0.w);
            bx[4]  = f2b(xv1.x); bx[5]  = f2b(xv1.y); bx[6]  = f2b(xv1.z); bx[7]  = f2b(xv1.w);
            bx[8]  = f2b(xv2.x); bx[9]  = f2b(xv2.y); bx[10] = f2b(xv2.z); bx[11] = f2b(xv2.w);
            bx[12] = f2b(xv3.x); bx[13] = f2b(xv3.y); bx[14] = f2b(xv3.z); bx[15] = f2b(xv3.w);
            unsigned short* xr = xs + srow * 64;
            *(uint4*)(xr + ((((sseg * 32)      ) ^ swzw) >> 1)) = *(uint4*)&bx[0];
            *(uint4*)(xr + ((((sseg * 32) + 16 ) ^ swzw) >> 1)) = *(uint4*)&bx[8];
            ((uint4*)ws)[tid]       = wv0;
            ((uint4*)ws)[tid + 256] = wv1;
        }
        __syncthreads();
#pragma unroll
        for (int ks = 0; ks < 2; ks++) {
            int kc = ks * 64 + quad * 16;           // logical byte col of fragment
            int co = (kc ^ swzr) >> 1;              // swizzled ushort offset
            bf16x8 a = *(const bf16x8*)(xs + (w * 16 + mr) * 64 + co);
#pragma unroll
            for (int nb = 0; nb < 4; nb++) {
                bf16x8 b = *(const bf16x8*)(ws + (nb * 16 + mr) * 64 + co);
                acc[nb] = __builtin_amdgcn_mfma_f32_16x16x32_bf16(a, b, acc[nb], 0, 0, 0);
            }
        }
    }
    __syncthreads();
    // D -> LDS tile (overlay hs[64][72] on smem)
    unsigned short (*hs)[72] = (unsigned short(*)[72])smem;
#pragma unroll
    for (int nb = 0; nb < 4; nb++)
#pragma unroll
        for (int r = 0; r < 4; r++)
            hs[w * 16 + quad * 4 + r][nb * 16 + mr] = f2b(acc[nb][r]);
    __syncthreads();
    // coalesced bf16 store: thread -> 32B (16 elems)
    {
        if (rok) {
            uint4 v0 = *(const uint4*)&hs[srow][sseg * 16];
            uint4 v1 = *(const uint4*)&hs[srow][sseg * 16 + 8];
            uint4* dst = (uint4*)(h1 + (size_t)(m0 + srow) * HC1 + sseg * 16);
            dst[0] = v0;
            dst[1] = v1;
        }
    }
    // fused alpha1: 512 (row,head) pairs per block
    for (int i = tid; i < 512; i += 256) {
        int row = i >> 3, hh = i & 7;
        if (m0 + row < Nn) {
            float s = 0.f, d = 0.f;
#pragma unroll
            for (int c = 0; c < 8; c++) {
                float v = b2f(hs[row][hh * 8 + c]);
                s += v * a_s[hh * 8 + c];
                d += v * a_d[hh * 8 + c];
            }
            as1[(size_t)(m0 + row) * NH1 + hh] = s;
            ad1[(size_t)(m0 + row) * NH1 + hh] = d;
        }
    }
}

// ---------------- layer-1 aggregation: edge-parallel per 64-node bucket ------------
// Block = bucket. 8-lane group owns one edge; lane cl owns head cl's 8 channels.
// Accumulate p*h into fp32 LDS via ds atomics; softmax denominator is PER-HEAD:
// psum1[node][head], each lane adds its own head's p. Epilogue: norm+bias+ELU ->
// h2b(fp16), plus fused as2/ad2 = <h2, W2 a_src2 / a_dst2>.
__global__ __launch_bounds__(256) void agg1b(const unsigned short* __restrict__ h1,
                                             const float* __restrict__ as1,
                                             const float* __restrict__ ad1,
                                             const int* __restrict__ bcnt, const int* __restrict__ bpk,
                                             const float* __restrict__ b1,
                                             const float* __restrict__ ws2, const float* __restrict__ wd2,
                                             unsigned short* __restrict__ h2b, float* __restrict__ as2,
                                             float* __restrict__ ad2, int Nn) {
    __shared__ float acc[64][68];       // padded stride: bank spread for atomics
    __shared__ float psum1[64][8];      // per-(node, head) softmax denominator
    __shared__ float ad1s[64][8];
    __shared__ float e0s[64][8];
    int tid = threadIdx.x;
    int b = blockIdx.x;
    int node0 = b << 6;
    // init acc with self rows (p = 1)
    {
        int n = tid >> 3, seg = tid & 7;   // 8 threads x 16B cover one 128B row
#pragma unroll
        for (int pass = 0; pass < 2; pass++) {
            int nn = pass * 32 + n;
            int gn = node0 + nn;
            uint4 hv = make_uint4(0, 0, 0, 0);
            if (gn < Nn) hv = *(const uint4*)(h1 + (size_t)gn * HC1 + seg * 8);
            const unsigned* hw = (const unsigned*)&hv;
#pragma unroll
            for (int j = 0; j < 4; j++) {
                acc[nn][seg * 8 + 2 * j]     = b2f((unsigned short)(hw[j] & 0xffff));
                acc[nn][seg * 8 + 2 * j + 1] = b2f((unsigned short)(hw[j] >> 16));
            }
        }
    }
    // per-dst alpha tables + per-head denominator init (self-loop p = 1)
    for (int i = tid; i < 512; i += 256) {
        int n = i >> 3, h = i & 7;
        int gn = node0 + n;
        float adv = 0.f, asv = 0.f;
        if (gn < Nn) { adv = ad1[(size_t)gn * 8 + h]; asv = as1[(size_t)gn * 8 + h]; }
        ad1s[n][h] = adv;
        e0s[n][h] = lrelu(asv + adv);
        psum1[n][h] = 1.f;
    }
    __syncthreads();
    int cb = min(bcnt[b], BCAP2);
    const int* bp = bpk + (size_t)b * BCAP2;
    int w = tid >> 6, lane = tid & 63;
    int g = lane >> 3, cl = lane & 7;
    for (int eb = w * 16; eb < cb; eb += 64) {     // 2 edges per group per iter
        int eA = eb + g, eB = eb + 8 + g;
        int pkA = (eA < cb) ? bp[eA] : -1;
        int pkB = (eB < cb) ? bp[eB] : -1;
        if (pkA >= 0) {
            int src = pkA >> 6, dl = pkA & 63;
            float p = __expf(lrelu(as1[(size_t)src * 8 + cl] + ad1s[dl][cl]) - e0s[dl][cl]);
            uint4 hv = *(const uint4*)(h1 + (size_t)src * HC1 + cl * 8);
            const unsigned* hw = (const unsigned*)&hv;
#pragma unroll
            for (int j = 0; j < 4; j++) {
                atomicAdd(&acc[dl][cl * 8 + 2 * j],     p * b2f((unsigned short)(hw[j] & 0xffff)));
                atomicAdd(&acc[dl][cl * 8 + 2 * j + 1], p * b2f((unsigned short)(hw[j] >> 16)));
            }
            atomicAdd(&psum1[dl][cl], p);
        }
        if (pkB >= 0) {
            int src = pkB >> 6, dl = pkB & 63;
            float p = __expf(lrelu(as1[(size_t)src * 8 + cl] + ad1s[dl][cl]) - e0s[dl][cl]);
            uint4 hv = *(const uint4*)(h1 + (size_t)src * HC1 + cl * 8);
            const unsigned* hw = (const unsigned*)&hv;
#pragma unroll
            for (int j = 0; j < 4; j++) {
                atomicAdd(&acc[dl][cl * 8 + 2 * j],     p * b2f((unsigned short)(hw[j] & 0xffff)));
                atomicAdd(&acc[dl][cl * 8 + 2 * j + 1], p * b2f((unsigned short)(hw[j] >> 16)));
            }
            atomicAdd(&psum1[dl][cl], p);
        }
    }
    __syncthreads();
    // epilogue: 32 threads per node (2ch each), 8 nodes per pass
    {
        int nloc = tid >> 5;
        int c2 = (tid & 31) * 2;          // c2 even -> c2, c2+1 in the same head
        int hh = c2 >> 3;
        float2 bv = *(const float2*)(b1 + c2);
        float2 wsv = *(const float2*)(ws2 + c2);
        float2 wdv = *(const float2*)(wd2 + c2);
#pragma unroll
        for (int pass = 0; pass < 8; pass++) {
            int n = pass * 8 + nloc;
            int gn = node0 + n;
            if (gn < Nn) {
                float inv = 1.f / (psum1[n][hh] + 1e-16f);
                float o0 = acc[n][c2] * inv + bv.x;
                float o1 = acc[n][c2 + 1] * inv + bv.y;
                o0 = o0 > 0.f ? o0 : __expf(o0) - 1.0f;     // ELU
                o1 = o1 > 0.f ? o1 : __expf(o1) - 1.0f;
                unsigned pk = (unsigned)f2h(o0) | ((unsigned)f2h(o1) << 16);
                *(unsigned*)(h2b + (size_t)gn * HC1 + c2) = pk;
                float va = o0 * wsv.x + o1 * wsv.y;
                float vd = o0 * wdv.x + o1 * wdv.y;
#pragma unroll
                for (int off = 1; off <= 16; off <<= 1) {
                    va += __shfl_xor(va, off, 64);
                    vd += __shfl_xor(vd, off, 64);
                }
                if ((tid & 31) == 0) { as2[gn] = va; ad2[gn] = vd; }
            }
        }
    }
}

// ---------------- layer-2 aggregation: edge-parallel per bucket + matvec + lsm -----
// Layer 2 has 1 head -> scalar denominator per node.
__global__ __launch_bounds__(256) void agg2b(const unsigned short* __restrict__ h2b,
                                             const float* __restrict__ as2,
                                             const float* __restrict__ ad2,
                                             const int* __restrict__ bcnt, const int* __restrict__ bpk,
                                             const float* __restrict__ W2, const float* __restrict__ b2,
                                             float* __restrict__ out, int Nn) {
    __shared__ float acc[64][68];
    __shared__ float psum[64];
    __shared__ float e0v[64], adv[64];
    __shared__ float W2s[HC1 * NC];
    int tid = threadIdx.x;
    int b = blockIdx.x;
    int node0 = b << 6;
    for (int i = tid; i < HC1 * NC; i += 256) W2s[i] = W2[i];
    {
        int n = tid >> 3, seg = tid & 7;
#pragma unroll
        for (int pass = 0; pass < 2; pass++) {
            int nn = pass * 32 + n;
            int gn = node0 + nn;
            uint4 hv = make_uint4(0, 0, 0, 0);
            if (gn < Nn) hv = *(const uint4*)(h2b + (size_t)gn * HC1 + seg * 8);
            const unsigned* hw = (const unsigned*)&hv;
#pragma unroll
            for (int j = 0; j < 4; j++) {
                union { unsigned u; __half2 h; } cv; cv.u = hw[j];
                float2 ff = __half22float2(cv.h);
                acc[nn][seg * 8 + 2 * j]     = ff.x;
                acc[nn][seg * 8 + 2 * j + 1] = ff.y;
            }
        }
        if (tid < 64) {
            psum[tid] = 1.f;
            int gn = node0 + tid;
            float a = 0.f, s = 0.f;
            if (gn < Nn) { a = ad2[gn]; s = as2[gn]; }
            adv[tid] = a;
            e0v[tid] = lrelu(s + a);
        }
    }
    __syncthreads();
    int cb = min(bcnt[b], BCAP2);
    const int* bp = bpk + (size_t)b * BCAP2;
    int w = tid >> 6, lane = tid & 63;
    int g = lane >> 3, cl = lane & 7;
    for (int eb = w * 16; eb < cb; eb += 64) {
        int eA = eb + g, eB = eb + 8 + g;
        int pkA = (eA < cb) ? bp[eA] : -1;
        int pkB = (eB < cb) ? bp[eB] : -1;
        if (pkA >= 0) {
            int src = pkA >> 6, dl = pkA & 63;
            float p = __expf(lrelu(as2[src] + adv[dl]) - e0v[dl]);
            uint4 hv = *(const uint4*)(h2b + (size_t)src * HC1 + cl * 8);
            const unsigned* hw = (const unsigned*)&hv;
#pragma unroll
            for (int j = 0; j < 4; j++) {
                union { unsigned u; __half2 h; } cv; cv.u = hw[j];
                float2 ff = __half22float2(cv.h);
                atomicAdd(&acc[dl][cl * 8 + 2 * j],     p * ff.x);
                atomicAdd(&acc[dl][cl * 8 + 2 * j + 1], p * ff.y);
            }
            if (cl == 0) atomicAdd(&psum[dl], p);
        }
        if (pkB >= 0) {
            int src = pkB >> 6, dl = pkB & 63;
            float p = __expf(lrelu(as2[src] + adv[dl]) - e0v[dl]);
            uint4 hv = *(const uint4*)(h2b + (size_t)src * HC1 + cl * 8);
            const unsigned* hw = (const unsigned*)&hv;
#pragma unroll
            for (int j = 0; j < 4; j++) {
                union { unsigned u; __half2 h; } cv; cv.u = hw[j];
                float2 ff = __half22float2(cv.h);
                atomicAdd(&acc[dl][cl * 8 + 2 * j],     p * ff.x);
                atomicAdd(&acc[dl][cl * 8 + 2 * j + 1], p * ff.y);
            }
            if (cl == 0) atomicAdd(&psum[dl], p);
        }
    }
    __syncthreads();
    // epilogue: wave handles 16 nodes; 64x40 matvec from LDS + log_softmax
    for (int i = 0; i < 16; i++) {
        int n = w * 16 + i;
        int gn = node0 + n;
        if (gn >= Nn) break;
        float inv = 1.f / (psum[n] + 1e-16f);
        float o = 0.f;
        if (lane < NC) {
            float dot = 0.f;
#pragma unroll
            for (int c = 0; c < HC1; c += 4) {
                float4 av = *(const float4*)&acc[n][c];
                dot += av.x * W2s[(c + 0) * NC + lane] + av.y * W2s[(c + 1) * NC + lane]
                     + av.z * W2s[(c + 2) * NC + lane] + av.w * W2s[(c + 3) * NC + lane];
            }
            o = b2[lane] + inv * dot;
        }
        float vm = (lane < NC) ? o : -1e30f;
#pragma unroll
        for (int off = 32; off; off >>= 1) vm = fmaxf(vm, __shfl_xor(vm, off, 64));
        float ex = (lane < NC) ? __expf(o - vm) : 0.f;
#pragma unroll
        for (int off = 32; off; off >>= 1) ex += __shfl_xor(ex, off, 64);
        float lsm = o - vm - __logf(ex);
        if (lane < NC) out[(size_t)gn * NC + lane] = lsm;
    }
}

// ---------------- host launch ----------------
extern "C" void kernel_launch(void* const* d_in, const int* in_sizes, int n_in,
                              void* d_out, int out_size, void* d_ws, size_t ws_size,
                              hipStream_t stream) {
    const float* x      = (const float*)d_in[0];
    const int*   ei     = (const int*)d_in[1];
    const float* W1     = (const float*)d_in[2];
    const float* a_src1 = (const float*)d_in[3];
    const float* a_dst1 = (const float*)d_in[4];
    const float* b1     = (const float*)d_in[5];
    const float* W2     = (const float*)d_in[6];
    const float* a_src2 = (const float*)d_in[7];
    const float* a_dst2 = (const float*)d_in[8];
    const float* b2     = (const float*)d_in[9];
    float* out = (float*)d_out;

    const int N = in_sizes[0] / F_IN;       // 100000
    const int E = in_sizes[1] / 2;          // 1600000
    const int NB2 = (N + 63) >> 6;          // 64-node buckets (1563)

    char* p = (char*)d_ws;
    auto alloc = [&](size_t bytes) -> void* {
        void* r = (void*)p;
        p += (bytes + 255) & ~(size_t)255;
        return r;
    };
    int* bcnt   = (int*)alloc((size_t)NB2 * 4);
    int* flag   = (int*)alloc(256);
    int* bpk    = (int*)alloc((size_t)NB2 * BCAP2 * 4);                 // 12.8 MB
    unsigned short* h1  = (unsigned short*)alloc((size_t)N * HC1 * 2);  // bf16
    float* as1  = (float*)alloc((size_t)N * NH1 * 4);
    float* ad1  = (float*)alloc((size_t)N * NH1 * 4);
    unsigned short* h2b = (unsigned short*)alloc((size_t)N * HC1 * 2);  // fp16
    float* as2  = (float*)alloc((size_t)N * 4);
    float* ad2  = (float*)alloc((size_t)N * 4);
    unsigned short* wst = (unsigned short*)alloc(8 * 64 * 64 * 2);      // 64KB, swizzled bf16 W1
    float* ws2  = (float*)alloc(HC1 * 4);
    float* wd2  = (float*)alloc(HC1 * 4);

    // --- prep + edge binning ---
    hipMemsetAsync(bcnt, 0, (size_t)NB2 * 4, stream);
    prep<<<17, 256, 0, stream>>>(W1, W2, a_src2, a_dst2, ei, wst, ws2, wd2, flag);
    scatter1<<<(E + RADIX_EPB - 1) / RADIX_EPB, 256, 0, stream>>>(ei, flag, bcnt, bpk, E, NB2);

    // --- layer 1 ---
    gemm1<<<(N + 63) / 64, 256, 0, stream>>>(x, wst, a_src1, a_dst1, h1, as1, ad1, N);
    agg1b<<<NB2, 256, 0, stream>>>(h1, as1, ad1, bcnt, bpk, b1, ws2, wd2, h2b, as2, ad2, N);

    // --- layer 2 ---
    agg2b<<<NB2, 256, 0, stream>>>(h2b, as2, ad2, bcnt, bpk, W2, b2, out, N);
}

// Round 6
// 581.787 us; speedup vs baseline: 2.9045x; 2.9045x over previous
//
#include <hip/hip_runtime.h>
#include <hip/hip_bf16.h>
#include <hip/hip_fp16.h>

// ---------------- problem constants (from reference) ----------------
// N = 100000 nodes, E = 1600000 edges, F_IN = 512, H1*C1 = 64, NUM_CLASSES = 40
#define F_IN 512
#define HC1 64          // 8 heads * 8 ch
#define NH1 8
#define NC 40
#define NEG_SLOPE 0.2f
#define SCAN_CHUNK 2048
#define RADIX_EPB 4096  // edges per block in scatter1
#define MAXNB 512       // max node buckets (256 nodes each)
#define BCAP 8192       // fixed bucket capacity (mean 4096, +64 sigma)

typedef short bf16x8 __attribute__((ext_vector_type(8)));
typedef float f32x4 __attribute__((ext_vector_type(4)));

static __device__ __forceinline__ unsigned short f2b(float f) {
    __hip_bfloat16 h = __float2bfloat16(f);      // RNE
    return *(unsigned short*)&h;
}
static __device__ __forceinline__ float b2f(unsigned short u) {
    union { unsigned int i; float f; } v;
    v.i = ((unsigned int)u) << 16;               // bf16 -> fp32 exact
    return v.f;
}
static __device__ __forceinline__ unsigned short f2h(float f) {
    __half h = __float2half(f);
    return *(unsigned short*)&h;
}

__device__ __forceinline__ float lrelu(float e) { return e > 0.f ? e : NEG_SLOPE * e; }

// ---------------- one-shot param prep + edge dtype detect (fused) ----------------
// blocks 0..15: wst (W1 bf16, k-major, XOR-swizzled LDS image); block 0 also ws2/wd2.
// block 16: int64 detection flag.
__global__ void prep(const float* __restrict__ W1, const float* __restrict__ W2,
                     const float* __restrict__ a_s2, const float* __restrict__ a_d2,
                     const int* __restrict__ ei,
                     unsigned short* __restrict__ wst, float* __restrict__ ws2,
                     float* __restrict__ wd2, int* __restrict__ flag) {
    if (blockIdx.x == 16) {
        __shared__ int found;
        if (threadIdx.x == 0) found = 0;
        __syncthreads();
        for (int i = threadIdx.x; i < 4096; i += 256) {
            if (ei[2 * i + 1] != 0) atomicOr(&found, 1);
        }
        __syncthreads();
        if (threadIdx.x == 0) *flag = (found == 0) ? 1 : 0;   // 1 => int64
        return;
    }
    int t = blockIdx.x * 256 + threadIdx.x;   // 16 x 256 = 4096 slots
    {
        int p  = t & 7;          // physical 16B slot
        int n  = (t >> 3) & 63;  // output column
        int kb = t >> 9;         // 64-wide k block, 0..7
        int l  = p ^ (n & 7);    // logical slot
        int k0 = kb * 64 + l * 8;
        unsigned short v[8];
#pragma unroll
        for (int j = 0; j < 8; j++) v[j] = f2b(W1[(size_t)(k0 + j) * HC1 + n]);
        *(uint4*)(wst + ((size_t)(kb * 64 + n) * 64 + p * 8)) = *(uint4*)v;
    }
    if (blockIdx.x == 0 && threadIdx.x < HC1) {
        int c = threadIdx.x;
        float s = 0.f, d = 0.f;
#pragma unroll
        for (int j = 0; j < NC; j++) {
            float w = W2[c * NC + j];
            s += w * a_s2[j];
            d += w * a_d2[j];
        }
        ws2[c] = s;
        wd2[c] = d;
    }
}

// ---------------- scatter pass 1: deg hist + bucket append (packed 4B records) -----
// record = (src << 8) | (dst & 255); bucket = dst >> 8.
__global__ __launch_bounds__(256) void scatter1(const int* __restrict__ ei, const int* __restrict__ flag,
                                                int* __restrict__ deg, int* __restrict__ bcnt,
                                                int* __restrict__ bpk, int E, int NB) {
    __shared__ int cnt[MAXNB];
    __shared__ int gb[MAXNB];
    int tid = threadIdx.x;
    for (int i = tid; i < NB; i += 256) cnt[i] = 0;
    __syncthreads();
    int f = *flag;
    int base = blockIdx.x * RADIX_EPB;
    int pk[16], bk[16], rv[16];
#pragma unroll
    for (int i = 0; i < 16; i++) {
        int e = base + i * 256 + tid;
        if (e < E) {
            int s, d;
            if (f) { s = ei[2 * e]; d = ei[2 * (E + e)]; }
            else   { s = ei[e];     d = ei[E + e]; }
            pk[i] = (s << 8) | (d & 255);
            bk[i] = d >> 8;
            rv[i] = atomicAdd(&cnt[bk[i]], 1);
            atomicAdd(&deg[d], 1);
        }
    }
    __syncthreads();
    for (int i = tid; i < NB; i += 256) {
        int c = cnt[i];
        gb[i] = c ? atomicAdd(&bcnt[i], c) : 0;
    }
    __syncthreads();
#pragma unroll
    for (int i = 0; i < 16; i++) {
        int e = base + i * 256 + tid;
        if (e < E) {
            int pos = gb[bk[i]] + rv[i];
            if (pos < BCAP)
                bpk[(size_t)bk[i] * BCAP + pos] = pk[i];
        }
    }
}

// ---------------- CSR rowptr: scans ----------------
__global__ __launch_bounds__(256) void scan1(const int* __restrict__ deg, int* __restrict__ rowptr,
                                             int* __restrict__ bsums, int n) {
    __shared__ int sbuf[256];
    int tid = threadIdx.x;
    int base = blockIdx.x * SCAN_CHUNK + tid * 8;
    int v[8];
#pragma unroll
    for (int j = 0; j < 8; j++) { int idx = base + j; v[j] = (idx < n) ? deg[idx] : 0; }
    int tsum = 0;
#pragma unroll
    for (int j = 0; j < 8; j++) tsum += v[j];
    sbuf[tid] = tsum;
    __syncthreads();
    for (int off = 1; off < 256; off <<= 1) {
        int t = (tid >= off) ? sbuf[tid - off] : 0;
        __syncthreads();
        sbuf[tid] += t;
        __syncthreads();
    }
    int run = sbuf[tid] - tsum;
#pragma unroll
    for (int j = 0; j < 8; j++) {
        run += v[j];
        int idx = base + j;
        if (idx < n) rowptr[1 + idx] = run;
    }
    if (tid == 255) bsums[blockIdx.x] = sbuf[255];
}

// scan2 folded in: wave 0 of every block redoes the tiny 64-wide block-sum scan.
__global__ __launch_bounds__(256) void scan23(int* __restrict__ rowptr,
                                              const int* __restrict__ bsums, int n, int nb) {
    __shared__ int soff[64];
    int tid = threadIdx.x;
    if (tid < 64) {
        int lane = tid;
        int v = (lane < nb) ? bsums[lane] : 0;
        int orig = v;
        for (int off = 1; off < 64; off <<= 1) {
            int t = __shfl_up(v, (unsigned)off, 64);
            if (lane >= off) v += t;
        }
        soff[lane] = v - orig;
    }
    __syncthreads();
    int i = blockIdx.x * 256 + tid;
    if (i < n) {
        rowptr[1 + i] += soff[i >> 11];
        if (i == 0) rowptr[0] = 0;
    }
}

// ---------------- scatter pass 2: per-bucket finalize (LDS cursors) ----------------
__global__ __launch_bounds__(256) void scatter2(const int* __restrict__ bpk,
                                                const int* __restrict__ bcnt,
                                                const int* __restrict__ rowptr,
                                                int* __restrict__ col, int Nn) {
    __shared__ int cur[256];
    int b = blockIdx.x;
    int node0 = b << 8;
    int tid = threadIdx.x;
    int nlast = min(node0 + 256, Nn);
    if (node0 + tid < nlast) cur[tid] = rowptr[node0 + tid];
    __syncthreads();
    int cnt = min(bcnt[b], BCAP);
    const int* bp = bpk + (size_t)b * BCAP;
    for (int j = tid; j < cnt; j += 256) {
        int pk = bp[j];
        int pos = atomicAdd(&cur[pk & 255], 1);
        col[pos] = (int)((unsigned)pk >> 8);
    }
}

// ---------------- GEMM1 (bf16 MFMA) + fused alpha1 ----------------
__global__ __launch_bounds__(256) void gemm1(const float* __restrict__ x,
                                             const unsigned short* __restrict__ wst,
                                             const float* __restrict__ a_s, const float* __restrict__ a_d,
                                             unsigned short* __restrict__ h1, float* __restrict__ as1,
                                             float* __restrict__ ad1, int Nn) {
    __shared__ __align__(16) unsigned short smem[8192];   // xs[64][64] | ws[64][64]
    unsigned short* xs = smem;          // swizzled A tile
    unsigned short* ws = smem + 4096;   // swizzled B tile (image == wst tile)
    int tid = threadIdx.x;
    int m0 = blockIdx.x * 64;
    int w = tid >> 6, lane = tid & 63;
    int quad = lane >> 4, mr = lane & 15;
    f32x4 acc[4];
#pragma unroll
    for (int i = 0; i < 4; i++) acc[i] = (f32x4){0.f, 0.f, 0.f, 0.f};

    int srow = tid >> 2;        // 0..63 staged row
    int sseg = tid & 3;         // 16-float segment within 64-wide k chunk
    bool rok = (m0 + srow) < Nn;
    const float* xrow = x + (size_t)(m0 + srow) * F_IN + sseg * 16;
    int swzw = (srow & 7) << 4;             // write-side XOR (bytes)
    int swzr = (mr & 7) << 4;               // read-side XOR (bytes)

    for (int kb = 0; kb < 8; kb++) {
        float4 xv0, xv1, xv2, xv3;
        if (rok) {
            const float4* xp = (const float4*)(xrow + kb * 64);
            xv0 = xp[0]; xv1 = xp[1]; xv2 = xp[2]; xv3 = xp[3];
        } else {
            xv0 = xv1 = xv2 = xv3 = make_float4(0.f, 0.f, 0.f, 0.f);
        }
        const uint4* wp = (const uint4*)(wst + (size_t)kb * 4096);
        uint4 wv0 = wp[tid];
        uint4 wv1 = wp[tid + 256];
        __syncthreads();   // previous iteration's MFMA reads complete
        {
            unsigned short bx[16];
            bx[0]  = f2b(xv0.x); bx[1]  = f2b(xv0.y); bx[2]  = f2b(xv0.z); bx[3]  = f2b(xv0.w);
            bx[4]  = f2b(xv1.x); bx[5]  = f2b(xv1.y); bx[6]  = f2b(xv1.z); bx[7]  = f2b(xv1.w);
            bx[8]  = f2b(xv2.x); bx[9]  = f2b(xv2.y); bx[10] = f2b(xv2.z); bx[11] = f2b(xv2.w);
            bx[12] = f2b(xv3.x); bx[13] = f2b(xv3.y); bx[14] = f2b(xv3.z); bx[15] = f2b(xv3.w);
            unsigned short* xr = xs + srow * 64;
            *(uint4*)(xr + ((((sseg * 32)      ) ^ swzw) >> 1)) = *(uint4*)&bx[0];
            *(uint4*)(xr + ((((sseg * 32) + 16 ) ^ swzw) >> 1)) = *(uint4*)&bx[8];
            ((uint4*)ws)[tid]       = wv0;
            ((uint4*)ws)[tid + 256] = wv1;
        }
        __syncthreads();
#pragma unroll
        for (int ks = 0; ks < 2; ks++) {
            int kc = ks * 64 + quad * 16;           // logical byte col of fragment
            int co = (kc ^ swzr) >> 1;              // swizzled ushort offset
            bf16x8 a = *(const bf16x8*)(xs + (w * 16 + mr) * 64 + co);
#pragma unroll
            for (int nb = 0; nb < 4; nb++) {
                bf16x8 b = *(const bf16x8*)(ws + (nb * 16 + mr) * 64 + co);
                acc[nb] = __builtin_amdgcn_mfma_f32_16x16x32_bf16(a, b, acc[nb], 0, 0, 0);
            }
        }
    }
    __syncthreads();
    // D -> LDS tile (overlay hs[64][72] on smem)
    unsigned short (*hs)[72] = (unsigned short(*)[72])smem;
#pragma unroll
    for (int nb = 0; nb < 4; nb++)
#pragma unroll
        for (int r = 0; r < 4; r++)
            hs[w * 16 + quad * 4 + r][nb * 16 + mr] = f2b(acc[nb][r]);
    __syncthreads();
    // coalesced bf16 store: thread -> 32B (16 elems)
    {
        if (rok) {
            uint4 v0 = *(const uint4*)&hs[srow][sseg * 16];
            uint4 v1 = *(const uint4*)&hs[srow][sseg * 16 + 8];
            uint4* dst = (uint4*)(h1 + (size_t)(m0 + srow) * HC1 + sseg * 16);
            dst[0] = v0;
            dst[1] = v1;
        }
    }
    // fused alpha1: 512 (row,head) pairs per block
    for (int i = tid; i < 512; i += 256) {
        int row = i >> 3, hh = i & 7;
        if (m0 + row < Nn) {
            float s = 0.f, d = 0.f;
#pragma unroll
            for (int c = 0; c < 8; c++) {
                float v = b2f(hs[row][hh * 8 + c]);
                s += v * a_s[hh * 8 + c];
                d += v * a_d[hh * 8 + c];
            }
            as1[(size_t)(m0 + row) * NH1 + hh] = s;
            ad1[(size_t)(m0 + row) * NH1 + hh] = d;
        }
    }
}

// ---------------- layer-1 aggregation, 2-edge-parallel (32 lanes x 2 bf16 ch) ------
// Wave = one dst node. half = lane>>5 processes edges idx = 2k+half; cl = lane&31
// owns channels {2cl, 2cl+1}. 16 edges per iteration -> 8 gathers in flight/lane.
__global__ __launch_bounds__(256) void agg1(const unsigned short* __restrict__ h1,
                                            const float* __restrict__ as1,
                                            const float* __restrict__ ad1, const int* __restrict__ rowptr,
                                            const int* __restrict__ col, const float* __restrict__ b1,
                                            const float* __restrict__ ws2, const float* __restrict__ wd2,
                                            unsigned short* __restrict__ h2b, float* __restrict__ as2,
                                            float* __restrict__ ad2, int Nn) {
    __shared__ float pbuf[4][NH1 * 68];
    int w = threadIdx.x >> 6;
    int wave = (blockIdx.x * 256 + threadIdx.x) >> 6;
    int lane = threadIdx.x & 63;
    if (wave >= Nn) return;
    int d = wave;
    int jb = rowptr[d], je = rowptr[d + 1];
    int half = lane >> 5;
    int cl = lane & 31;
    int head = cl >> 2;                       // channel pair {2cl,2cl+1} -> head
    const float4* as4 = (const float4*)as1;
    const float4* ad4 = (const float4*)ad1;

    float4 dd0 = ad4[d * 2], dd1 = ad4[d * 2 + 1];
    float adh[8] = {dd0.x, dd0.y, dd0.z, dd0.w, dd1.x, dd1.y, dd1.z, dd1.w};
    float4 sd0 = as4[d * 2], sd1 = as4[d * 2 + 1];
    float svh[8] = {sd0.x, sd0.y, sd0.z, sd0.w, sd1.x, sd1.y, sd1.z, sd1.w};
    float e0[8];
#pragma unroll
    for (int h = 0; h < NH1; h++) e0[h] = lrelu(svh[h] + adh[h]);

    float acc0, acc1, ss;
    {
        unsigned gv = *(const unsigned*)(h1 + (size_t)d * HC1 + 2 * cl);
        union { unsigned i; float f; } lo, hi;
        lo.i = gv << 16; hi.i = gv & 0xffff0000u;
        if (half == 0) { acc0 = lo.f; acc1 = hi.f; ss = 1.f; }
        else           { acc0 = 0.f;  acc1 = 0.f;  ss = 0.f; }
    }
    float* pb = pbuf[w];

    for (int c0 = jb; c0 < je; c0 += 64) {
        int nc = min(64, je - c0);
        int srcv = d;
        if (lane < nc) {
            unsigned u = (unsigned)col[c0 + lane];
            srcv = (u < (unsigned)Nn) ? (int)u : d;     // guard vs (impossible) bucket overflow
            float4 a0 = as4[srcv * 2], a1 = as4[srcv * 2 + 1];
            float ev[8] = {a0.x, a0.y, a0.z, a0.w, a1.x, a1.y, a1.z, a1.w};
#pragma unroll
            for (int h = 0; h < NH1; h++)
                pb[h * 68 + lane] = __expf(lrelu(ev[h] + adh[h]) - e0[h]);
        } else {
#pragma unroll
            for (int h = 0; h < NH1; h++) pb[h * 68 + lane] = 0.f;
        }
        int ncp = (nc + 15) & ~15;
        for (int jj = 0; jj < ncp; jj += 16) {      // 16 edges/iter: 8 per half
            int sarr[8];
            float parr[8];
            unsigned gvv[8];
#pragma unroll
            for (int u4 = 0; u4 < 8; u4++) {
                int idx = jj + 2 * u4 + half;
                sarr[u4] = __shfl(srcv, idx, 64);
                parr[u4] = pb[head * 68 + idx];
            }
#pragma unroll
            for (int u4 = 0; u4 < 8; u4++)
                gvv[u4] = *(const unsigned*)(h1 + (size_t)sarr[u4] * HC1 + 2 * cl);
#pragma unroll
            for (int u4 = 0; u4 < 8; u4++) {
                union { unsigned i; float f; } lo, hi;
                lo.i = gvv[u4] << 16; hi.i = gvv[u4] & 0xffff0000u;
                acc0 += parr[u4] * lo.f;
                acc1 += parr[u4] * hi.f;
                ss += parr[u4];
            }
        }
    }
    acc0 += __shfl_xor(acc0, 32, 64);
    acc1 += __shfl_xor(acc1, 32, 64);
    ss   += __shfl_xor(ss, 32, 64);
    float inv = 1.f / (ss + 1e-16f);
    float o0 = acc0 * inv + b1[2 * cl];
    float o1 = acc1 * inv + b1[2 * cl + 1];
    o0 = o0 > 0.f ? o0 : __expf(o0) - 1.0f;     // ELU
    o1 = o1 > 0.f ? o1 : __expf(o1) - 1.0f;
    if (half == 0) {
        unsigned pk = (unsigned)f2h(o0) | ((unsigned)f2h(o1) << 16);
        *(unsigned*)(h2b + (size_t)d * HC1 + 2 * cl) = pk;
    }
    // fused: as2[d] = <h2[d], W2 a_src2>, ad2[d] = <h2[d], W2 a_dst2>
    float va = o0 * ws2[2 * cl] + o1 * ws2[2 * cl + 1];
    float vd = o0 * wd2[2 * cl] + o1 * wd2[2 * cl + 1];
#pragma unroll
    for (int off = 16; off; off >>= 1) {
        va += __shfl_xor(va, off, 64);
        vd += __shfl_xor(vd, off, 64);
    }
    if (lane == 0) { as2[d] = va; ad2[d] = vd; }
}

// ---------------- layer-2 aggregation, 2-edge-parallel + W2 matvec + log_softmax ---
__global__ __launch_bounds__(256) void agg2(const unsigned short* __restrict__ h2b,
                                            const float* __restrict__ as2,
                                            const float* __restrict__ ad2, const int* __restrict__ rowptr,
                                            const int* __restrict__ col, const float* __restrict__ W2,
                                            const float* __restrict__ b2,
                                            float* __restrict__ out, int Nn) {
    __shared__ float pbuf[4][64];
    __shared__ float smv[4][64];
    __shared__ float W2s[HC1 * NC];
    int tid = threadIdx.x;
    for (int i = tid; i < HC1 * NC; i += 256) W2s[i] = W2[i];
    __syncthreads();
    int w = tid >> 6;
    int wave = (blockIdx.x * 256 + tid) >> 6;
    int lane = tid & 63;
    if (wave >= Nn) return;
    int d = wave;
    int jb = rowptr[d], je = rowptr[d + 1];
    int half = lane >> 5;
    int cl = lane & 31;
    float adv = ad2[d];
    float e0 = lrelu(as2[d] + adv);
    float acc0, acc1, ss;
    {
        unsigned gv = *(const unsigned*)(h2b + (size_t)d * HC1 + 2 * cl);
        union { unsigned u; __half2 h; } cv; cv.u = gv;
        float2 ff = __half22float2(cv.h);
        if (half == 0) { acc0 = ff.x; acc1 = ff.y; ss = 1.f; }
        else           { acc0 = 0.f;  acc1 = 0.f;  ss = 0.f; }
    }
    float* pb = pbuf[w];

    for (int c0 = jb; c0 < je; c0 += 64) {
        int nc = min(64, je - c0);
        int srcv = d;
        if (lane < nc) {
            unsigned u = (unsigned)col[c0 + lane];
            srcv = (u < (unsigned)Nn) ? (int)u : d;
            pb[lane] = __expf(lrelu(as2[srcv] + adv) - e0);
        } else {
            pb[lane] = 0.f;
        }
        int ncp = (nc + 15) & ~15;
        for (int jj = 0; jj < ncp; jj += 16) {      // 16 edges/iter: 8 per half
            int sarr[8];
            float parr[8];
            unsigned gvv[8];
#pragma unroll
            for (int u4 = 0; u4 < 8; u4++) {
                int idx = jj + 2 * u4 + half;
                sarr[u4] = __shfl(srcv, idx, 64);
                parr[u4] = pb[idx];
            }
#pragma unroll
            for (int u4 = 0; u4 < 8; u4++)
                gvv[u4] = *(const unsigned*)(h2b + (size_t)sarr[u4] * HC1 + 2 * cl);
#pragma unroll
            for (int u4 = 0; u4 < 8; u4++) {
                union { unsigned u; __half2 h; } cv; cv.u = gvv[u4];
                float2 ff = __half22float2(cv.h);
                acc0 += parr[u4] * ff.x;
                acc1 += parr[u4] * ff.y;
                ss += parr[u4];
            }
        }
    }
    acc0 += __shfl_xor(acc0, 32, 64);
    acc1 += __shfl_xor(acc1, 32, 64);
    ss   += __shfl_xor(ss, 32, 64);
    float inv = 1.f / (ss + 1e-16f);
    if (half == 0) {
        smv[w][2 * cl]     = acc0 * inv;      // same-wave produce->consume
        smv[w][2 * cl + 1] = acc1 * inv;
    }
    float o = 0.f;
    if (lane < NC) {
        o = b2[lane];
        const float* sv = smv[w];
#pragma unroll
        for (int c = 0; c < HC1; c++) o += sv[c] * W2s[c * NC + lane];
    }
    float vm = (lane < NC) ? o : -1e30f;
#pragma unroll
    for (int off = 32; off; off >>= 1) vm = fmaxf(vm, __shfl_xor(vm, off, 64));
    float ex = (lane < NC) ? __expf(o - vm) : 0.f;
#pragma unroll
    for (int off = 32; off; off >>= 1) ex += __shfl_xor(ex, off, 64);
    float lsm = o - vm - __logf(ex);
    if (lane < NC) out[(size_t)d * NC + lane] = lsm;
}

// ---------------- host launch ----------------
extern "C" void kernel_launch(void* const* d_in, const int* in_sizes, int n_in,
                              void* d_out, int out_size, void* d_ws, size_t ws_size,
                              hipStream_t stream) {
    const float* x      = (const float*)d_in[0];
    const int*   ei     = (const int*)d_in[1];
    const float* W1     = (const float*)d_in[2];
    const float* a_src1 = (const float*)d_in[3];
    const float* a_dst1 = (const float*)d_in[4];
    const float* b1     = (const float*)d_in[5];
    const float* W2     = (const float*)d_in[6];
    const float* a_src2 = (const float*)d_in[7];
    const float* a_dst2 = (const float*)d_in[8];
    const float* b2     = (const float*)d_in[9];
    float* out = (float*)d_out;

    const int N = in_sizes[0] / F_IN;       // 100000
    const int E = in_sizes[1] / 2;          // 1600000
    const int NB = (N + 255) >> 8;          // 256-node buckets (391)

    char* p = (char*)d_ws;
    auto alloc = [&](size_t bytes) -> void* {
        void* r = (void*)p;
        p += (bytes + 255) & ~(size_t)255;
        return r;
    };
    int* deg    = (int*)alloc((size_t)N * 4);
    int* bcnt   = (int*)alloc((size_t)MAXNB * 4);      // adjacent to deg: one memset
    int* rowptr = (int*)alloc(((size_t)N + 1) * 4);
    int* bsums  = (int*)alloc(64 * 4);
    int* flag   = (int*)alloc(256);
    int* bpk    = (int*)alloc((size_t)NB * BCAP * 4);                   // 12.8 MB packed
    int* col    = (int*)alloc((size_t)E * 4);
    unsigned short* h1  = (unsigned short*)alloc((size_t)N * HC1 * 2);  // bf16
    float* as1  = (float*)alloc((size_t)N * NH1 * 4);
    float* ad1  = (float*)alloc((size_t)N * NH1 * 4);
    unsigned short* h2b = (unsigned short*)alloc((size_t)N * HC1 * 2);  // fp16
    float* as2  = (float*)alloc((size_t)N * 4);
    float* ad2  = (float*)alloc((size_t)N * 4);
    unsigned short* wst = (unsigned short*)alloc(8 * 64 * 64 * 2);      // 64KB, swizzled bf16 W1
    float* ws2  = (float*)alloc(HC1 * 4);
    float* wd2  = (float*)alloc(HC1 * 4);

    // --- CSR build + param prep ---
    size_t zlen = (size_t)((char*)(bcnt + MAXNB) - (char*)deg);
    hipMemsetAsync(deg, 0, zlen, stream);
    prep<<<17, 256, 0, stream>>>(W1, W2, a_src2, a_dst2, ei, wst, ws2, wd2, flag);
    scatter1<<<(E + RADIX_EPB - 1) / RADIX_EPB, 256, 0, stream>>>(ei, flag, deg, bcnt, bpk, E, NB);
    int nb = (N + SCAN_CHUNK - 1) / SCAN_CHUNK;
    scan1<<<nb, 256, 0, stream>>>(deg, rowptr, bsums, N);
    scan23<<<(N + 255) / 256, 256, 0, stream>>>(rowptr, bsums, N, nb);
    scatter2<<<NB, 256, 0, stream>>>(bpk, bcnt, rowptr, col, N);

    // --- layer 1 (gemm1 fuses alpha1; agg1 fuses layer-2 alpha prologue) ---
    gemm1<<<(N + 63) / 64, 256, 0, stream>>>(x, wst, a_src1, a_dst1, h1, as1, ad1, N);
    agg1<<<(N + 3) / 4, 256, 0, stream>>>(h1, as1, ad1, rowptr, col, b1, ws2, wd2, h2b, as2, ad2, N);

    // --- layer 2: aggregate in h2-space, matvec + log_softmax fused ---
    agg2<<<(N + 3) / 4, 256, 0, stream>>>(h2b, as2, ad2, rowptr, col, W2, b2, out, N);
}